// Round 4
// baseline (867.000 us; speedup 1.0000x reference)
//
#include <hip/hip_runtime.h>

typedef unsigned char u8;
typedef unsigned short u16;
typedef unsigned int u32;
typedef __attribute__((ext_vector_type(8))) short short8;
typedef __attribute__((ext_vector_type(4))) u16 ushort4_t;
typedef __attribute__((ext_vector_type(4))) float fx4;
typedef __attribute__((ext_vector_type(8))) int int8v;

#define DIMK 2048
#define NBLK 2000
// fp8 pre-scale: store 32*x as e4m3, MX scale byte 122 = 2^-5 per operand -> exact cancel
#define SCL 32.0f
#define SCLBYTE 0x7A7A7A7A

typedef const __attribute__((address_space(1))) void* gp_t;
typedef __attribute__((address_space(3))) void* lp_t;

__device__ __forceinline__ u16 f2bf(float f) {
  u32 u = __float_as_uint(f);
  u32 r = (u + 0x7fffu + ((u >> 16) & 1u)) >> 16;
  return (u16)r;
}

__device__ __forceinline__ u32 pk4_fp8(float a, float b, float c, float d) {
  int v = 0;
  v = __builtin_amdgcn_cvt_pk_fp8_f32(a, b, v, false);  // bytes 0-1
  v = __builtin_amdgcn_cvt_pk_fp8_f32(c, d, v, true);   // bytes 2-3
  return (u32)v;
}

__device__ __forceinline__ u32 fkey(float f) {
  u32 u = __float_as_uint(f);
  return (u & 0x80000000u) ? ~u : (u | 0x80000000u);
}
__device__ __forceinline__ float dekey(u32 k) {
  u32 u = (k & 0x80000000u) ? (k ^ 0x80000000u) : ~k;
  return __uint_as_float(u);
}

// ---------- bf16 128x128 tile (kept for gram) ----------
__device__ __forceinline__ void gemm_tile(const u16* __restrict__ Abase,
                                          const u16* __restrict__ Bbase,
                                          int row0, int col0,
                                          u16* lsA, u16* lsB,
                                          fx4 acc[4][4])
{
  const int tid  = threadIdx.x;
  const int wv   = tid >> 6;
  const int lane = tid & 63;
  const int wr   = wv & 1, wc = wv >> 1;
  const int quad = lane >> 4, lc = lane & 15;

  const int srow = wv * 32 + (lane >> 2);
  const int skel = (((lane & 3) ^ ((lane >> 3) & 3)) * 8);
  const u16* gA0 = Abase + (size_t)(row0 + srow) * DIMK + skel;
  const u16* gA1 = gA0 + (size_t)16 * DIMK;
  const u16* gB0 = Bbase + (size_t)(col0 + srow) * DIMK + skel;
  const u16* gB1 = gB0 + (size_t)16 * DIMK;
  u16* lA0 = lsA + wv * 1024;
  u16* lA1 = lsA + wv * 1024 + 512;
  u16* lB0 = lsB + wv * 1024;
  u16* lB1 = lsB + wv * 1024 + 512;

  const int fIntra = lc * 32 + ((quad ^ ((lc >> 1) & 3)) * 8);

#pragma unroll
  for (int mi = 0; mi < 4; mi++)
#pragma unroll
    for (int ni = 0; ni < 4; ni++)
      acc[mi][ni] = fx4{0.f, 0.f, 0.f, 0.f};

  for (int k0 = 0; k0 < DIMK; k0 += 32) {
    __syncthreads();
    __builtin_amdgcn_global_load_lds((gp_t)gA0, (lp_t)lA0, 16, 0, 0);
    __builtin_amdgcn_global_load_lds((gp_t)gA1, (lp_t)lA1, 16, 0, 0);
    __builtin_amdgcn_global_load_lds((gp_t)gB0, (lp_t)lB0, 16, 0, 0);
    __builtin_amdgcn_global_load_lds((gp_t)gB1, (lp_t)lB1, 16, 0, 0);
    gA0 += 32; gA1 += 32; gB0 += 32; gB1 += 32;
    __syncthreads();
    short8 af[4], bfr[4];
#pragma unroll
    for (int mi = 0; mi < 4; mi++)
      af[mi] = *(const short8*)(lsA + (wr * 4 + mi) * 512 + fIntra);
#pragma unroll
    for (int ni = 0; ni < 4; ni++)
      bfr[ni] = *(const short8*)(lsB + (wc * 4 + ni) * 512 + fIntra);
#pragma unroll
    for (int mi = 0; mi < 4; mi++)
#pragma unroll
      for (int ni = 0; ni < 4; ni++)
        acc[mi][ni] = __builtin_amdgcn_mfma_f32_16x16x32_bf16(af[mi], bfr[ni], acc[mi][ni], 0, 0, 0);
  }
}

// one wave per row -> fp8 (scaled by 32, normalized)
__global__ __launch_bounds__(256) void norm_rows_x(const float* __restrict__ x,
                                                   u8* __restrict__ Xq)
{
  const int wv = threadIdx.x >> 6, lane = threadIdx.x & 63;
  const int row = blockIdx.x * 4 + wv;
  const float4* xr = (const float4*)(x + (size_t)row * DIMK);
  float4 v[8];
  float ss = 0.f;
#pragma unroll
  for (int j = 0; j < 8; j++) {
    v[j] = xr[j * 64 + lane];
    ss += v[j].x*v[j].x + v[j].y*v[j].y + v[j].z*v[j].z + v[j].w*v[j].w;
  }
#pragma unroll
  for (int off = 1; off < 64; off <<= 1) ss += __shfl_xor(ss, off);
  float inv = SCL / fmaxf(sqrtf(ss), 1e-12f);
  u32* o = (u32*)(Xq + (size_t)row * DIMK);
#pragma unroll
  for (int j = 0; j < 8; j++)
    o[j * 64 + lane] = pk4_fp8(v[j].x * inv, v[j].y * inv, v[j].z * inv, v[j].w * inv);
}

// W: fp8 normalized+scaled (Wq) for att, bf16 raw (Wb) for gram. Rows >= NBLK -> 0.
__global__ __launch_bounds__(256) void norm_rows_w(const float* __restrict__ w,
                                                   u8* __restrict__ Wq,
                                                   u16* __restrict__ Wb)
{
  const int wv = threadIdx.x >> 6, lane = threadIdx.x & 63;
  const int row = blockIdx.x * 4 + wv;
  u32* oq = (u32*)(Wq + (size_t)row * DIMK);
  ushort4_t* ob_ = (ushort4_t*)(Wb + (size_t)row * DIMK);
  if (row < NBLK) {
    const float4* wr_ = (const float4*)(w + (size_t)row * DIMK);
    float4 v[8];
    float ss = 0.f;
#pragma unroll
    for (int j = 0; j < 8; j++) {
      v[j] = wr_[j * 64 + lane];
      ss += v[j].x*v[j].x + v[j].y*v[j].y + v[j].z*v[j].z + v[j].w*v[j].w;
    }
#pragma unroll
    for (int off = 1; off < 64; off <<= 1) ss += __shfl_xor(ss, off);
    float inv = SCL / fmaxf(sqrtf(ss), 1e-12f);
#pragma unroll
    for (int j = 0; j < 8; j++) {
      oq[j * 64 + lane] = pk4_fp8(v[j].x * inv, v[j].y * inv, v[j].z * inv, v[j].w * inv);
      ushort4_t tb;
      tb[0] = f2bf(v[j].x); tb[1] = f2bf(v[j].y);
      tb[2] = f2bf(v[j].z); tb[3] = f2bf(v[j].w);
      ob_[j * 64 + lane] = tb;
    }
  } else {
    ushort4_t z = ushort4_t{0, 0, 0, 0};
#pragma unroll
    for (int j = 0; j < 8; j++) { oq[j * 64 + lane] = 0u; ob_[j * 64 + lane] = z; }
  }
}

__global__ __launch_bounds__(256) void gram_kernel(const u16* __restrict__ Wb,
                                                   float* __restrict__ divsum)
{
  __shared__ __align__(16) u16 lsA[4096];
  __shared__ __align__(16) u16 lsB[4096];
  fx4 acc[4][4];
  const int i0 = blockIdx.y * 128, j0 = blockIdx.x * 128;
  gemm_tile(Wb, Wb, i0, j0, lsA, lsB, acc);
  const int tid = threadIdx.x, wv = tid >> 6, lane = tid & 63;
  const int wr = wv & 1, wc = wv >> 1, quad = lane >> 4, lc = lane & 15;
  float local = 0.f;
#pragma unroll
  for (int mi = 0; mi < 4; mi++) {
#pragma unroll
    for (int ni = 0; ni < 4; ni++) {
#pragma unroll
      for (int r = 0; r < 4; r++) {
        int i = i0 + wr * 64 + mi * 16 + quad * 4 + r;
        int j = j0 + wc * 64 + ni * 16 + lc;
        float g = acc[mi][ni][r];
        float d = (i == j && i < NBLK) ? 1.0f : 0.0f;
        float e = g - d;
        local += e * e;
      }
    }
  }
#pragma unroll
  for (int off = 1; off < 64; off <<= 1) local += __shfl_xor(local, off);
  if (lane == 0) atomicAdd(divsum, local);
}

// ---------- MX-fp8 att: 128x128 tile, 16x16x128 f8f6f4, K-loop of 16 ----------
// LDS per operand: 8 blocks of (16 rows x 128 B). Granule(16B) slot within a
// row: slot = c ^ (((row>>1)&3)<<1)  (pair-preserving XOR swizzle).
//  - staging inst covers 8 rows (1 KB): lane l -> row l>>3, slot l&7, so
//    global c_src = (l&7) ^ (((l>>4)&3)<<1); 8-lane groups stay on one 128-B line.
//  - fragment read: lane(quad,lc) reads 32 B at row lc, pair (quad ^ ((lc>>1)&3)):
//    aligned 32-B (k-order preserved), bank classes distinct per 8-lane phase.
__global__ __launch_bounds__(256) void att_kernel(const u8* __restrict__ Xq,
                                                  const u8* __restrict__ Wq,
                                                  const int* __restrict__ mask,
                                                  u32* __restrict__ top1k,
                                                  float* __restrict__ s)
{
  __shared__ __align__(32) u8 lsA[16384];
  __shared__ __align__(32) u8 lsB[16384];
  __shared__ float sMask[128];
  const int xb = blockIdx.x, yb = blockIdx.y;
  const int tid = threadIdx.x;
  if (tid < 128) sMask[tid] = (float)mask[yb * 128 + tid];
  const int wv = tid >> 6, lane = tid & 63;
  const int wr = wv & 1, wc = wv >> 1, quad = lane >> 4, lc = lane & 15;

  const int csrc = (lane & 7) ^ (((lane >> 4) & 3) << 1);
  const u8* gA = Xq + (size_t)(yb * 128 + wv * 32 + (lane >> 3)) * DIMK + csrc * 16;
  const u8* gB = Wq + (size_t)(xb * 128 + wv * 32 + (lane >> 3)) * DIMK + csrc * 16;
  u8* lA = lsA + wv * 4096;
  u8* lB = lsB + wv * 4096;

  const int fIntra = lc * 128 + ((quad ^ ((lc >> 1) & 3)) << 5);
  const int fA = (wr * 4) * 2048 + fIntra;
  const int fB = (wc * 4) * 2048 + fIntra;

  fx4 acc[4][4];
#pragma unroll
  for (int mi = 0; mi < 4; mi++)
#pragma unroll
    for (int ni = 0; ni < 4; ni++)
      acc[mi][ni] = fx4{0.f, 0.f, 0.f, 0.f};

  for (int k0 = 0; k0 < 16; k0++) {
    __syncthreads();
#pragma unroll
    for (int i = 0; i < 4; i++) {
      __builtin_amdgcn_global_load_lds((gp_t)(gA + (size_t)i * 8 * DIMK), (lp_t)(lA + i * 1024), 16, 0, 0);
      __builtin_amdgcn_global_load_lds((gp_t)(gB + (size_t)i * 8 * DIMK), (lp_t)(lB + i * 1024), 16, 0, 0);
    }
    gA += 128; gB += 128;
    __syncthreads();
    int8v af[4], bq[4];
#pragma unroll
    for (int mi = 0; mi < 4; mi++)
      af[mi] = *(const int8v*)(lsA + fA + mi * 2048);
#pragma unroll
    for (int ni = 0; ni < 4; ni++)
      bq[ni] = *(const int8v*)(lsB + fB + ni * 2048);
#pragma unroll
    for (int mi = 0; mi < 4; mi++)
#pragma unroll
      for (int ni = 0; ni < 4; ni++)
        acc[mi][ni] = __builtin_amdgcn_mfma_scale_f32_16x16x128_f8f6f4(
            af[mi], bq[ni], acc[mi][ni], 0, 0, 0, SCLBYTE, 0, SCLBYTE);
  }

  const int colbase = xb * 128 + wc * 64;

  // per-row max over this tile's 128 cols -> atomicMax on monotone key
#pragma unroll
  for (int mi = 0; mi < 4; mi++) {
#pragma unroll
    for (int r = 0; r < 4; r++) {
      float v = -3.0e38f;
#pragma unroll
      for (int ni = 0; ni < 4; ni++) {
        int col = colbase + ni * 16 + lc;
        float av = acc[mi][ni][r];
        v = (col < NBLK && av > v) ? av : v;
      }
      v = fmaxf(v, __shfl_xor(v, 1));
      v = fmaxf(v, __shfl_xor(v, 2));
      v = fmaxf(v, __shfl_xor(v, 4));
      v = fmaxf(v, __shfl_xor(v, 8));
      if (lc == 0) {
        int row = yb * 128 + wr * 64 + mi * 16 + quad * 4 + r;
        atomicMax(&top1k[row], fkey(v));
      }
    }
  }

  // masked column sums for first half-batch -> s[b][col]
  if (yb < 128) {
    const int b = yb >> 3;
#pragma unroll
    for (int ni = 0; ni < 4; ni++) {
      float sv = 0.f;
#pragma unroll
      for (int mi = 0; mi < 4; mi++) {
#pragma unroll
        for (int r = 0; r < 4; r++)
          sv += sMask[wr * 64 + mi * 16 + quad * 4 + r] * acc[mi][ni][r];
      }
      sv += __shfl_xor(sv, 16);
      sv += __shfl_xor(sv, 32);
      int col = colbase + ni * 16 + lc;
      if (quad == 0 && col < NBLK)
        atomicAdd(&s[b * 2048 + col], sv);
    }
  }
}

__global__ __launch_bounds__(256) void softmax_kernel(const float* __restrict__ s,
                                                      float* __restrict__ tmp)
{
  const int b = blockIdx.x, tid = threadIdx.x;
  const float* sb = s + b * 2048;
  __shared__ float red[4];
  float mx = -3.0e38f;
  for (int n = tid; n < NBLK; n += 256) mx = fmaxf(mx, sb[n]);
#pragma unroll
  for (int off = 1; off < 64; off <<= 1) mx = fmaxf(mx, __shfl_xor(mx, off));
  if ((tid & 63) == 0) red[tid >> 6] = mx;
  __syncthreads();
  mx = fmaxf(fmaxf(red[0], red[1]), fmaxf(red[2], red[3]));
  __syncthreads();
  float se = 0.f;
  for (int n = tid; n < NBLK; n += 256) se += expf(sb[n] - mx);
#pragma unroll
  for (int off = 1; off < 64; off <<= 1) se += __shfl_xor(se, off);
  if ((tid & 63) == 0) red[tid >> 6] = se;
  __syncthreads();
  se = red[0] + red[1] + red[2] + red[3];
  float scale = 1.0f / (se * 16.0f);
  for (int n = tid; n < NBLK; n += 256) atomicAdd(&tmp[n], expf(sb[n] - mx) * scale);
}

__global__ __launch_bounds__(1024) void finalize_kernel(const u32* __restrict__ top1k,
                                                        const int* __restrict__ mask,
                                                        const float* __restrict__ tmp,
                                                        const float* __restrict__ divsum,
                                                        float* __restrict__ out)
{
  const int tid = threadIdx.x;
  __shared__ float sMin[32];
  __shared__ float sSq[16];
  const int b = tid >> 5, li = tid & 31;
  float mn = 3.0e38f;
  for (int t = li; t < 1024; t += 32) {
    int idx = b * 1024 + t;
    if (mask[idx] > 0) mn = fminf(mn, dekey(top1k[idx]));
  }
#pragma unroll
  for (int off = 1; off < 32; off <<= 1) mn = fminf(mn, __shfl_xor(mn, off));
  if (li == 0) sMin[b] = mn;
  float ssq = 0.f;
  for (int n = tid; n < NBLK; n += 1024) { float v = tmp[n]; ssq += v * v; }
#pragma unroll
  for (int off = 1; off < 64; off <<= 1) ssq += __shfl_xor(ssq, off);
  if ((tid & 63) == 0) sSq[tid >> 6] = ssq;
  __syncthreads();
  if (tid == 0) {
    float m0 = 0.f, m1 = 0.f;
    for (int i = 0; i < 16; i++) { m0 += sMin[i]; m1 += sMin[16 + i]; }
    m0 *= (1.0f / 16.0f); m1 *= (1.0f / 16.0f);
    float sq = 0.f;
    for (int i = 0; i < 16; i++) sq += sSq[i];
    out[0] = 0.2f * sqrtf(divsum[0]);
    out[1] = 2.0f - m0 + m1;
    out[2] = 0.5f * sqrtf(sq);
  }
}

extern "C" void kernel_launch(void* const* d_in, const int* in_sizes, int n_in,
                              void* d_out, int out_size, void* d_ws, size_t ws_size,
                              hipStream_t stream) {
  const float* x    = (const float*)d_in[0];   // [32,1024,2048] f32
  const int*   mask = (const int*)d_in[1];     // [32,1024] i32
  const float* w    = (const float*)d_in[2];   // [2000,2048] f32
  float* out = (float*)d_out;

  char* ws = (char*)d_ws;
  // layout: [top1k 128KB][s 128KB][tmp 8KB][divsum 256B][Xq 64MB][Wq 4MB][Wb 8MB]
  u32*   top1k  = (u32*)(ws);
  float* s      = (float*)(ws + 131072);
  float* tmp    = (float*)(ws + 262144);
  float* divsum = (float*)(ws + 270336);
  u8*    Xq     = (u8*)(ws + 270592);
  u8*    Wq     = (u8*)(ws + 270592 + 67108864ull);
  u16*   Wb     = (u16*)(ws + 270592 + 67108864ull + 4194304ull);

  hipMemsetAsync(ws, 0, 270592, stream);  // zero accumulators + top1 keys

  norm_rows_w<<<dim3(512), dim3(256), 0, stream>>>(w, Wq, Wb);
  norm_rows_x<<<dim3(8192), dim3(256), 0, stream>>>(x, Xq);
  gram_kernel<<<dim3(16, 16), dim3(256), 0, stream>>>(Wb, divsum);
  att_kernel<<<dim3(16, 256), dim3(256), 0, stream>>>(Xq, Wq, mask, top1k, s);
  softmax_kernel<<<dim3(16), dim3(256), 0, stream>>>(s, tmp);
  finalize_kernel<<<dim3(1), dim3(1024), 0, stream>>>(top1k, mask, tmp, divsum, out);
}

// Round 5
// 851.961 us; speedup vs baseline: 1.0177x; 1.0177x over previous
//
#include <hip/hip_runtime.h>

typedef unsigned char u8;
typedef unsigned short u16;
typedef unsigned int u32;
typedef __attribute__((ext_vector_type(8))) short short8;
typedef __attribute__((ext_vector_type(4))) u16 ushort4_t;
typedef __attribute__((ext_vector_type(4))) float fx4;
typedef __attribute__((ext_vector_type(16))) float fx16;
typedef __attribute__((ext_vector_type(4))) int int4v;
typedef __attribute__((ext_vector_type(8))) int int8v;

#define DIMK 2048
#define NBLK 2000
// fp8 pre-scale: store 32*x as e4m3, MX scale byte 122 = 2^-5 per operand -> exact cancel
#define SCL 32.0f
#define SCLBYTE 0x7A7A7A7A

typedef const __attribute__((address_space(1))) void* gp_t;
typedef __attribute__((address_space(3))) void* lp_t;

__device__ __forceinline__ u16 f2bf(float f) {
  u32 u = __float_as_uint(f);
  u32 r = (u + 0x7fffu + ((u >> 16) & 1u)) >> 16;
  return (u16)r;
}

__device__ __forceinline__ u32 pk4_fp8(float a, float b, float c, float d) {
  int v = 0;
  v = __builtin_amdgcn_cvt_pk_fp8_f32(a, b, v, false);  // bytes 0-1
  v = __builtin_amdgcn_cvt_pk_fp8_f32(c, d, v, true);   // bytes 2-3
  return (u32)v;
}

__device__ __forceinline__ u32 fkey(float f) {
  u32 u = __float_as_uint(f);
  return (u & 0x80000000u) ? ~u : (u | 0x80000000u);
}
__device__ __forceinline__ float dekey(u32 k) {
  u32 u = (k & 0x80000000u) ? (k ^ 0x80000000u) : ~k;
  return __uint_as_float(u);
}

// ---------- bf16 128x128 tile (kept for gram) ----------
__device__ __forceinline__ void gemm_tile(const u16* __restrict__ Abase,
                                          const u16* __restrict__ Bbase,
                                          int row0, int col0,
                                          u16* lsA, u16* lsB,
                                          fx4 acc[4][4])
{
  const int tid  = threadIdx.x;
  const int wv   = tid >> 6;
  const int lane = tid & 63;
  const int wr   = wv & 1, wc = wv >> 1;
  const int quad = lane >> 4, lc = lane & 15;

  const int srow = wv * 32 + (lane >> 2);
  const int skel = (((lane & 3) ^ ((lane >> 3) & 3)) * 8);
  const u16* gA0 = Abase + (size_t)(row0 + srow) * DIMK + skel;
  const u16* gA1 = gA0 + (size_t)16 * DIMK;
  const u16* gB0 = Bbase + (size_t)(col0 + srow) * DIMK + skel;
  const u16* gB1 = gB0 + (size_t)16 * DIMK;
  u16* lA0 = lsA + wv * 1024;
  u16* lA1 = lsA + wv * 1024 + 512;
  u16* lB0 = lsB + wv * 1024;
  u16* lB1 = lsB + wv * 1024 + 512;

  const int fIntra = lc * 32 + ((quad ^ ((lc >> 1) & 3)) * 8);

#pragma unroll
  for (int mi = 0; mi < 4; mi++)
#pragma unroll
    for (int ni = 0; ni < 4; ni++)
      acc[mi][ni] = fx4{0.f, 0.f, 0.f, 0.f};

  for (int k0 = 0; k0 < DIMK; k0 += 32) {
    __syncthreads();
    __builtin_amdgcn_global_load_lds((gp_t)gA0, (lp_t)lA0, 16, 0, 0);
    __builtin_amdgcn_global_load_lds((gp_t)gA1, (lp_t)lA1, 16, 0, 0);
    __builtin_amdgcn_global_load_lds((gp_t)gB0, (lp_t)lB0, 16, 0, 0);
    __builtin_amdgcn_global_load_lds((gp_t)gB1, (lp_t)lB1, 16, 0, 0);
    gA0 += 32; gA1 += 32; gB0 += 32; gB1 += 32;
    __syncthreads();
    short8 af[4], bfr[4];
#pragma unroll
    for (int mi = 0; mi < 4; mi++)
      af[mi] = *(const short8*)(lsA + (wr * 4 + mi) * 512 + fIntra);
#pragma unroll
    for (int ni = 0; ni < 4; ni++)
      bfr[ni] = *(const short8*)(lsB + (wc * 4 + ni) * 512 + fIntra);
#pragma unroll
    for (int mi = 0; mi < 4; mi++)
#pragma unroll
      for (int ni = 0; ni < 4; ni++)
        acc[mi][ni] = __builtin_amdgcn_mfma_f32_16x16x32_bf16(af[mi], bfr[ni], acc[mi][ni], 0, 0, 0);
  }
}

// one wave per row -> fp8 (scaled by 32, normalized)
__global__ __launch_bounds__(256) void norm_rows_x(const float* __restrict__ x,
                                                   u8* __restrict__ Xq)
{
  const int wv = threadIdx.x >> 6, lane = threadIdx.x & 63;
  const int row = blockIdx.x * 4 + wv;
  const float4* xr = (const float4*)(x + (size_t)row * DIMK);
  float4 v[8];
  float ss = 0.f;
#pragma unroll
  for (int j = 0; j < 8; j++) {
    v[j] = xr[j * 64 + lane];
    ss += v[j].x*v[j].x + v[j].y*v[j].y + v[j].z*v[j].z + v[j].w*v[j].w;
  }
#pragma unroll
  for (int off = 1; off < 64; off <<= 1) ss += __shfl_xor(ss, off);
  float inv = SCL / fmaxf(sqrtf(ss), 1e-12f);
  u32* o = (u32*)(Xq + (size_t)row * DIMK);
#pragma unroll
  for (int j = 0; j < 8; j++)
    o[j * 64 + lane] = pk4_fp8(v[j].x * inv, v[j].y * inv, v[j].z * inv, v[j].w * inv);
}

// W: fp8 normalized+scaled (Wq) for att, bf16 raw (Wb) for gram. Rows >= NBLK -> 0.
__global__ __launch_bounds__(256) void norm_rows_w(const float* __restrict__ w,
                                                   u8* __restrict__ Wq,
                                                   u16* __restrict__ Wb)
{
  const int wv = threadIdx.x >> 6, lane = threadIdx.x & 63;
  const int row = blockIdx.x * 4 + wv;
  u32* oq = (u32*)(Wq + (size_t)row * DIMK);
  ushort4_t* ob_ = (ushort4_t*)(Wb + (size_t)row * DIMK);
  if (row < NBLK) {
    const float4* wr_ = (const float4*)(w + (size_t)row * DIMK);
    float4 v[8];
    float ss = 0.f;
#pragma unroll
    for (int j = 0; j < 8; j++) {
      v[j] = wr_[j * 64 + lane];
      ss += v[j].x*v[j].x + v[j].y*v[j].y + v[j].z*v[j].z + v[j].w*v[j].w;
    }
#pragma unroll
    for (int off = 1; off < 64; off <<= 1) ss += __shfl_xor(ss, off);
    float inv = SCL / fmaxf(sqrtf(ss), 1e-12f);
#pragma unroll
    for (int j = 0; j < 8; j++) {
      oq[j * 64 + lane] = pk4_fp8(v[j].x * inv, v[j].y * inv, v[j].z * inv, v[j].w * inv);
      ushort4_t tb;
      tb[0] = f2bf(v[j].x); tb[1] = f2bf(v[j].y);
      tb[2] = f2bf(v[j].z); tb[3] = f2bf(v[j].w);
      ob_[j * 64 + lane] = tb;
    }
  } else {
    ushort4_t z = ushort4_t{0, 0, 0, 0};
#pragma unroll
    for (int j = 0; j < 8; j++) { oq[j * 64 + lane] = 0u; ob_[j * 64 + lane] = z; }
  }
}

__global__ __launch_bounds__(256) void gram_kernel(const u16* __restrict__ Wb,
                                                   float* __restrict__ divsum)
{
  __shared__ __align__(16) u16 lsA[4096];
  __shared__ __align__(16) u16 lsB[4096];
  fx4 acc[4][4];
  const int i0 = blockIdx.y * 128, j0 = blockIdx.x * 128;
  gemm_tile(Wb, Wb, i0, j0, lsA, lsB, acc);
  const int tid = threadIdx.x, wv = tid >> 6, lane = tid & 63;
  const int wr = wv & 1, wc = wv >> 1, quad = lane >> 4, lc = lane & 15;
  float local = 0.f;
#pragma unroll
  for (int mi = 0; mi < 4; mi++) {
#pragma unroll
    for (int ni = 0; ni < 4; ni++) {
#pragma unroll
      for (int r = 0; r < 4; r++) {
        int i = i0 + wr * 64 + mi * 16 + quad * 4 + r;
        int j = j0 + wc * 64 + ni * 16 + lc;
        float g = acc[mi][ni][r];
        float d = (i == j && i < NBLK) ? 1.0f : 0.0f;
        float e = g - d;
        local += e * e;
      }
    }
  }
#pragma unroll
  for (int off = 1; off < 64; off <<= 1) local += __shfl_xor(local, off);
  if (lane == 0) atomicAdd(divsum, local);
}

// ---------- MX-fp8 att: 128x128 tile, 32x32x64 f8f6f4, 64x64 per wave ----------
// LDS per operand: 4 blocks of [32 rows x 64 B]; 16-B granule slot within a
// row: s = c ^ ((row>>1)&3).
//  - staging (dest forced base+16*lane): lane l -> row l>>2 (+16 per inst),
//    slot l&3, so global c_src = (l&3) ^ ((l>>3)&3); each 4-lane group covers
//    one contiguous 64-B line.
//  - fragment: lane(h=lane>>5, r=lane&31) needs granules {2h, 2h+1} of row r,
//    read as two 16-B loads at slots (2h+j)^((r>>1)&3); start-bank classes
//    are distinct within every consecutive-8-lane phase -> conflict-free.
// Operand layout (extrapolated, same family as verified 16x16x128):
//   A[row=lane&31][k=(lane>>5)*32 + j]. C/D (measured m74/m101):
//   col=lane&31, row=(reg&3)+8*(reg>>2)+4*(lane>>5).
__global__ __launch_bounds__(256) void att_kernel(const u8* __restrict__ Xq,
                                                  const u8* __restrict__ Wq,
                                                  const int* __restrict__ mask,
                                                  u32* __restrict__ top1k,
                                                  float* __restrict__ s)
{
  __shared__ __align__(32) u8 lsA[8192];
  __shared__ __align__(32) u8 lsB[8192];
  __shared__ float sMask[128];
  const int xb = blockIdx.x, yb = blockIdx.y;
  const int tid = threadIdx.x;
  if (tid < 128) sMask[tid] = (float)mask[yb * 128 + tid];
  const int wv = tid >> 6, lane = tid & 63;
  const int wr = wv & 1, wc = wv >> 1;
  const int h = lane >> 5, cl = lane & 31;

  const int csrc = (lane & 3) ^ ((lane >> 3) & 3);
  const u8* gA = Xq + (size_t)(yb * 128 + wv * 32 + (lane >> 2)) * DIMK + csrc * 16;
  const u8* gB = Wq + (size_t)(xb * 128 + wv * 32 + (lane >> 2)) * DIMK + csrc * 16;
  u8* lA = lsA + wv * 2048;
  u8* lB = lsB + wv * 2048;

  // fragment read offsets (bytes) within a 32-row block
  const int rsw = (lane >> 1) & 3;
  const int f0 = cl * 64 + (((2 * h) ^ rsw) << 4);
  const int f1 = cl * 64 + (((2 * h + 1) ^ rsw) << 4);

  fx16 acc[2][2];
#pragma unroll
  for (int mi = 0; mi < 2; mi++)
#pragma unroll
    for (int ni = 0; ni < 2; ni++)
#pragma unroll
      for (int r = 0; r < 16; r++)
        acc[mi][ni][r] = 0.f;

  for (int k0 = 0; k0 < 32; k0++) {
    __syncthreads();
    __builtin_amdgcn_global_load_lds((gp_t)gA, (lp_t)lA, 16, 0, 0);
    __builtin_amdgcn_global_load_lds((gp_t)(gA + (size_t)16 * DIMK), (lp_t)(lA + 1024), 16, 0, 0);
    __builtin_amdgcn_global_load_lds((gp_t)gB, (lp_t)lB, 16, 0, 0);
    __builtin_amdgcn_global_load_lds((gp_t)(gB + (size_t)16 * DIMK), (lp_t)(lB + 1024), 16, 0, 0);
    gA += 64; gB += 64;
    __syncthreads();
    int8v af[2], bq[2];
#pragma unroll
    for (int mi = 0; mi < 2; mi++) {
      const u8* base = lsA + (wr * 2 + mi) * 2048;
      int4v lo = *(const int4v*)(base + f0);
      int4v hi = *(const int4v*)(base + f1);
      af[mi] = int8v{lo[0], lo[1], lo[2], lo[3], hi[0], hi[1], hi[2], hi[3]};
    }
#pragma unroll
    for (int ni = 0; ni < 2; ni++) {
      const u8* base = lsB + (wc * 2 + ni) * 2048;
      int4v lo = *(const int4v*)(base + f0);
      int4v hi = *(const int4v*)(base + f1);
      bq[ni] = int8v{lo[0], lo[1], lo[2], lo[3], hi[0], hi[1], hi[2], hi[3]};
    }
#pragma unroll
    for (int mi = 0; mi < 2; mi++)
#pragma unroll
      for (int ni = 0; ni < 2; ni++)
        acc[mi][ni] = __builtin_amdgcn_mfma_scale_f32_32x32x64_f8f6f4(
            af[mi], bq[ni], acc[mi][ni], 0, 0, 0, SCLBYTE, 0, SCLBYTE);
  }

  const int colbase = xb * 128 + wc * 64;

  // per-row max over this tile's 128 cols -> atomicMax on monotone key
#pragma unroll
  for (int mi = 0; mi < 2; mi++) {
#pragma unroll
    for (int reg = 0; reg < 16; reg++) {
      float v = -3.0e38f;
#pragma unroll
      for (int ni = 0; ni < 2; ni++) {
        int col = colbase + ni * 32 + cl;
        float av = acc[mi][ni][reg];
        v = (col < NBLK && av > v) ? av : v;
      }
      v = fmaxf(v, __shfl_xor(v, 1));
      v = fmaxf(v, __shfl_xor(v, 2));
      v = fmaxf(v, __shfl_xor(v, 4));
      v = fmaxf(v, __shfl_xor(v, 8));
      v = fmaxf(v, __shfl_xor(v, 16));
      if (cl == 0) {
        int row = yb * 128 + wr * 64 + mi * 32 + (reg & 3) + 8 * (reg >> 2) + 4 * h;
        atomicMax(&top1k[row], fkey(v));
      }
    }
  }

  // masked column sums for first half-batch -> s[b][col]
  if (yb < 128) {
    const int b = yb >> 3;
#pragma unroll
    for (int ni = 0; ni < 2; ni++) {
      float sv = 0.f;
#pragma unroll
      for (int mi = 0; mi < 2; mi++) {
#pragma unroll
        for (int reg = 0; reg < 16; reg++)
          sv += sMask[wr * 64 + mi * 32 + (reg & 3) + 8 * (reg >> 2) + 4 * h] * acc[mi][ni][reg];
      }
      sv += __shfl_xor(sv, 32);
      int col = colbase + ni * 32 + cl;
      if (h == 0 && col < NBLK)
        atomicAdd(&s[b * 2048 + col], sv);
    }
  }
}

__global__ __launch_bounds__(256) void softmax_kernel(const float* __restrict__ s,
                                                      float* __restrict__ tmp)
{
  const int b = blockIdx.x, tid = threadIdx.x;
  const float* sb = s + b * 2048;
  __shared__ float red[4];
  float mx = -3.0e38f;
  for (int n = tid; n < NBLK; n += 256) mx = fmaxf(mx, sb[n]);
#pragma unroll
  for (int off = 1; off < 64; off <<= 1) mx = fmaxf(mx, __shfl_xor(mx, off));
  if ((tid & 63) == 0) red[tid >> 6] = mx;
  __syncthreads();
  mx = fmaxf(fmaxf(red[0], red[1]), fmaxf(red[2], red[3]));
  __syncthreads();
  float se = 0.f;
  for (int n = tid; n < NBLK; n += 256) se += expf(sb[n] - mx);
#pragma unroll
  for (int off = 1; off < 64; off <<= 1) se += __shfl_xor(se, off);
  if ((tid & 63) == 0) red[tid >> 6] = se;
  __syncthreads();
  se = red[0] + red[1] + red[2] + red[3];
  float scale = 1.0f / (se * 16.0f);
  for (int n = tid; n < NBLK; n += 256) atomicAdd(&tmp[n], expf(sb[n] - mx) * scale);
}

__global__ __launch_bounds__(1024) void finalize_kernel(const u32* __restrict__ top1k,
                                                        const int* __restrict__ mask,
                                                        const float* __restrict__ tmp,
                                                        const float* __restrict__ divsum,
                                                        float* __restrict__ out)
{
  const int tid = threadIdx.x;
  __shared__ float sMin[32];
  __shared__ float sSq[16];
  const int b = tid >> 5, li = tid & 31;
  float mn = 3.0e38f;
  for (int t = li; t < 1024; t += 32) {
    int idx = b * 1024 + t;
    if (mask[idx] > 0) mn = fminf(mn, dekey(top1k[idx]));
  }
#pragma unroll
  for (int off = 1; off < 32; off <<= 1) mn = fminf(mn, __shfl_xor(mn, off));
  if (li == 0) sMin[b] = mn;
  float ssq = 0.f;
  for (int n = tid; n < NBLK; n += 1024) { float v = tmp[n]; ssq += v * v; }
#pragma unroll
  for (int off = 1; off < 64; off <<= 1) ssq += __shfl_xor(ssq, off);
  if ((tid & 63) == 0) sSq[tid >> 6] = ssq;
  __syncthreads();
  if (tid == 0) {
    float m0 = 0.f, m1 = 0.f;
    for (int i = 0; i < 16; i++) { m0 += sMin[i]; m1 += sMin[16 + i]; }
    m0 *= (1.0f / 16.0f); m1 *= (1.0f / 16.0f);
    float sq = 0.f;
    for (int i = 0; i < 16; i++) sq += sSq[i];
    out[0] = 0.2f * sqrtf(divsum[0]);
    out[1] = 2.0f - m0 + m1;
    out[2] = 0.5f * sqrtf(sq);
  }
}

extern "C" void kernel_launch(void* const* d_in, const int* in_sizes, int n_in,
                              void* d_out, int out_size, void* d_ws, size_t ws_size,
                              hipStream_t stream) {
  const float* x    = (const float*)d_in[0];   // [32,1024,2048] f32
  const int*   mask = (const int*)d_in[1];     // [32,1024] i32
  const float* w    = (const float*)d_in[2];   // [2000,2048] f32
  float* out = (float*)d_out;

  char* ws = (char*)d_ws;
  // layout: [top1k 128KB][s 128KB][tmp 8KB][divsum 256B][Xq 64MB][Wq 4MB][Wb 8MB]
  u32*   top1k  = (u32*)(ws);
  float* s      = (float*)(ws + 131072);
  float* tmp    = (float*)(ws + 262144);
  float* divsum = (float*)(ws + 270336);
  u8*    Xq     = (u8*)(ws + 270592);
  u8*    Wq     = (u8*)(ws + 270592 + 67108864ull);
  u16*   Wb     = (u16*)(ws + 270592 + 67108864ull + 4194304ull);

  hipMemsetAsync(ws, 0, 270592, stream);  // zero accumulators + top1 keys

  norm_rows_w<<<dim3(512), dim3(256), 0, stream>>>(w, Wq, Wb);
  norm_rows_x<<<dim3(8192), dim3(256), 0, stream>>>(x, Xq);
  gram_kernel<<<dim3(16, 16), dim3(256), 0, stream>>>(Wb, divsum);
  att_kernel<<<dim3(16, 256), dim3(256), 0, stream>>>(Xq, Wq, mask, top1k, s);
  softmax_kernel<<<dim3(16), dim3(256), 0, stream>>>(s, tmp);
  finalize_kernel<<<dim3(1), dim3(1024), 0, stream>>>(top1k, mask, tmp, divsum, out);
}